// Round 8
// baseline (465.738 us; speedup 1.0000x reference)
//
#include <hip/hip_runtime.h>
#include <math.h>

#define NROWS   512
#define NSTEPS  256
#define PKSTEPS (NSTEPS + 2)   // +2 pad steps so prefetch can overrun unguarded

// Packet stream: [step][slot 0..4][tid 0..255] float4, slot-major per step so
// each wave's load of one slot is 64 consecutive float4 (perfect coalescing).
//  slot0 = (E0.t, E0.r, E1.t, E1.r)          even-layer coeffs, pair 64w+l
//  slot1 = (P0[R0].re, .im, P0[R0+1].re, .im) phase layer 2i
//  slot2 = (O0 cT.t, cT.r, cB.t, cB.r)        odd layer 2i (cB = pair-1, baked in)
//  slot3 = P1 rows                            phase layer 2i+1
//  slot4 = O1 cT/cB                           odd layer 2i+1
__device__ float4 g_pk[PKSTEPS * 5 * 256];
__device__ float2 g_io[1024];   // [0,512) = Pin per row, [512,1024) = Pout per row

// ---------------- coefficient precompute ----------------

__device__ __forceinline__ float2 pc_coef(float th, float loss) {
  float a = sqrtf(1.0f - loss);
  float s, c;
  sincosf(th, &s, &c);
  return make_float2(a * c, a * s);
}
__device__ __forceinline__ float2 mmi_coef(float loss, float imb) {
  float a = sqrtf(1.0f - loss);
  return make_float2(a * sqrtf(0.5f + imb), a * sqrtf(0.5f - imb));
}

__global__ void precomp_kernel(const float* __restrict__ thf,
                               const float* __restrict__ thio,
                               const float* __restrict__ lpf,
                               const float* __restrict__ lpio,
                               const float* __restrict__ le,
                               const float* __restrict__ lo,
                               const float* __restrict__ ie,
                               const float* __restrict__ io2) {
  const int b   = blockIdx.x;
  const int tid = threadIdx.x;
  if (b >= NSTEPS) {
    // io blocks: j in [0,512); thio/lpio are (2,512) flattened
    int j = (b - NSTEPS) * 256 + tid;
    g_io[j]       = pc_coef(thio[j],       lpio[j]);        // Pin
    g_io[j + 512] = pc_coef(thio[j + 512], lpio[j + 512]);  // Pout
    return;
  }
  const int i  = b;
  const int w  = tid >> 6, l = tid & 63;
  const int R0 = 128 * w + 2 * l;
  const int p  = 64 * w + l;
  const int L0 = 2 * i, L1 = 2 * i + 1;

  float2 e0  = mmi_coef(le[L0 * 256 + p], ie[L0 * 256 + p]);
  float2 e1  = mmi_coef(le[L1 * 256 + p], ie[L1 * 256 + p]);
  float2 p0a = pc_coef(thf[L0 * 512 + R0],     lpf[L0 * 512 + R0]);
  float2 p0b = pc_coef(thf[L0 * 512 + R0 + 1], lpf[L0 * 512 + R0 + 1]);
  float2 p1a = pc_coef(thf[L1 * 512 + R0],     lpf[L1 * 512 + R0]);
  float2 p1b = pc_coef(thf[L1 * 512 + R0 + 1], lpf[L1 * 512 + R0 + 1]);
  float2 one = make_float2(1.0f, 0.0f);
  float2 o0T = (p <= 254) ? mmi_coef(lo[L0 * 255 + p],     io2[L0 * 255 + p])     : one;
  float2 o0B = (p >= 1)   ? mmi_coef(lo[L0 * 255 + p - 1], io2[L0 * 255 + p - 1]) : one;
  float2 o1T = (p <= 254) ? mmi_coef(lo[L1 * 255 + p],     io2[L1 * 255 + p])     : one;
  float2 o1B = (p >= 1)   ? mmi_coef(lo[L1 * 255 + p - 1], io2[L1 * 255 + p - 1]) : one;

  float4* base = g_pk + (i * 5) * 256 + tid;
  base[0]        = make_float4(e0.x,  e0.y,  e1.x,  e1.y);
  base[256]      = make_float4(p0a.x, p0a.y, p0b.x, p0b.y);
  base[2 * 256]  = make_float4(o0T.x, o0T.y, o0B.x, o0B.y);
  base[3 * 256]  = make_float4(p1a.x, p1a.y, p1b.x, p1b.y);
  base[4 * 256]  = make_float4(o1T.x, o1T.y, o1B.x, o1B.y);
}

// ---------------- column propagation ----------------
// Block = 256 threads = 4 waves = ONE column (2048 waves total = 2 waves/SIMD).
// Wave w owns rows 128w..128w+127; lane l owns rows R0=128w+2l, R0+1.
// 2-step-ahead register prefetch of the 5-float4 packet hides L2/HBM latency;
// 2 waves/SIMD hide shuffle/barrier stalls.

__device__ __forceinline__ void cmul(float2& v, float ar, float ai) {
  float xr = ar * v.x - ai * v.y;
  float xi = ar * v.y + ai * v.x;
  v.x = xr; v.y = xi;
}
__device__ __forceinline__ void mmix(float2& top, float2& bot, float t, float r) {
  float a = t * top.x - r * bot.y;
  float b = t * top.y + r * bot.x;
  float c = t * bot.x - r * top.y;
  float d = t * bot.y + r * top.x;
  top.x = a; top.y = b; bot.x = c; bot.y = d;
}
// v' = t*v + i r*o
__device__ __forceinline__ void upd(float2& v, float t, float r, float2 o) {
  float xr = t * v.x - r * o.y;
  float xi = t * v.y + r * o.x;
  v.x = xr; v.y = xi;
}

__global__ __launch_bounds__(256) void prop_kernel(float* __restrict__ out,
                                                   int write_complex) {
  __shared__ float2 sUp[2][4];  // [sid][wave]: old row 128w+127
  __shared__ float2 sDn[2][4];  // [sid][wave]: old row 128w
  const int tid = threadIdx.x;
  const int l = tid & 63, w = tid >> 6;
  const int R0 = 128 * w + 2 * l;
  const int col = blockIdx.x;

  float2 v0, v1;
  v0 = (col == R0)     ? make_float2(1.0f, 0.0f) : make_float2(0.0f, 0.0f);
  v1 = (col == R0 + 1) ? make_float2(1.0f, 0.0f) : make_float2(0.0f, 0.0f);

  auto odd = [&](float4 c, int sid) {
    // old neighbor state, gathered before any update
    float2 nb, pt;
    nb.x = __shfl_down(v0.x, 1); nb.y = __shfl_down(v0.y, 1);
    pt.x = __shfl_up(v1.x, 1);   pt.y = __shfl_up(v1.y, 1);
    if (l == 0)  sDn[sid][w] = v0;
    if (l == 63) sUp[sid][w] = v1;
    __syncthreads();
    if (l == 63 && w < 3) nb = sDn[sid][w + 1];
    if (l == 0 && w > 0)  pt = sUp[sid][w - 1];
    if (!(w == 3 && l == 63))            // row 511 passes through
      upd(v1, c.x, c.y, nb);
    if (!(w == 0 && l == 0))             // row 0 passes through
      upd(v0, c.z, c.w, pt);
  };

  auto step = [&](float4 f0, float4 f1, float4 f2, float4 f3, float4 f4) {
    mmix(v0, v1, f0.x, f0.y);            // E(2i)
    cmul(v0, f1.x, f1.y);                // P(2i)
    cmul(v1, f1.z, f1.w);
    mmix(v0, v1, f0.z, f0.w);            // E(2i+1)
    odd(f2, 0);                          // O(2i)
    cmul(v0, f3.x, f3.y);                // P(2i+1)
    cmul(v1, f3.z, f3.w);
    odd(f4, 1);                          // O(2i+1)
  };

  // Pin
  {
    float4 a = *(const float4*)(g_io + R0);
    cmul(v0, a.x, a.y);
    cmul(v1, a.z, a.w);
  }

  const float4* P = g_pk + tid;   // step stride = 5*256 float4
  // prologue: prefetch steps 0 and 1
  float4 a0 = P[0],        a1 = P[256],        a2 = P[512],
         a3 = P[768],      a4 = P[1024];
  float4 b0 = P[1280],     b1 = P[1280+256],   b2 = P[1280+512],
         b3 = P[1280+768], b4 = P[1280+1024];

  #pragma unroll 1
  for (int i = 0; i < NSTEPS; i += 2) {
    const float4* Q = P + (i + 2) * 1280;     // pad steps make this safe
    float4 n0 = Q[0], n1 = Q[256], n2 = Q[512], n3 = Q[768], n4 = Q[1024];
    step(a0, a1, a2, a3, a4);
    a0 = n0; a1 = n1; a2 = n2; a3 = n3; a4 = n4;
    const float4* R = P + (i + 3) * 1280;
    n0 = R[0]; n1 = R[256]; n2 = R[512]; n3 = R[768]; n4 = R[1024];
    step(b0, b1, b2, b3, b4);
    b0 = n0; b1 = n1; b2 = n2; b3 = n3; b4 = n4;
  }

  // Pout
  {
    float4 a = *(const float4*)(g_io + 512 + R0);
    cmul(v0, a.x, a.y);
    cmul(v1, a.z, a.w);
  }

  if (write_complex) {
    float2* o = (float2*)out;
    o[(R0 + 0) * NROWS + col] = v0;
    o[(R0 + 1) * NROWS + col] = v1;
  } else {
    // d_out = 262144 floats: real part of the complex64 matrix
    out[(R0 + 0) * NROWS + col] = v0.x;
    out[(R0 + 1) * NROWS + col] = v1.x;
  }
}

// ---------------- launch ----------------

extern "C" void kernel_launch(void* const* d_in, const int* in_sizes, int n_in,
                              void* d_out, int out_size, void* d_ws, size_t ws_size,
                              hipStream_t stream) {
  const float* thf  = (const float*)d_in[0];  // thetas_full     (512,512)
  const float* thio = (const float*)d_in[1];  // thetas_inout    (2,512)
  const float* lpf  = (const float*)d_in[2];  // pc_losses_full  (512,512)
  const float* lpio = (const float*)d_in[3];  // pc_losses_inout (2,512)
  const float* le   = (const float*)d_in[4];  // mmi_losses_even (512,256)
  const float* lo   = (const float*)d_in[5];  // mmi_losses_odd  (512,255)
  const float* ie   = (const float*)d_in[6];  // mmi_imb_even    (512,256)
  const float* io2  = (const float*)d_in[7];  // mmi_imb_odd     (512,255)

  const int write_complex = (out_size >= 2 * NROWS * NROWS) ? 1 : 0;

  precomp_kernel<<<NSTEPS + 2, 256, 0, stream>>>(
      thf, thio, lpf, lpio, le, lo, ie, io2);
  prop_kernel<<<NROWS, 256, 0, stream>>>((float*)d_out, write_complex);
}

// Round 9
// 256.472 us; speedup vs baseline: 1.8159x; 1.8159x over previous
//
#include <hip/hip_runtime.h>
#include <math.h>

#define NROWS   512
#define NSTEPS  256
#define PKSTEPS (NSTEPS + 2)   // +2 pad steps so prefetch can overrun unguarded
#define PKF4    1024           // float4 per step: 4 slots x 256 threads
#define NREP    8              // one stream replica per XCD

// Packet stream, replicated per XCD. Per step, per thread (tid = 64w+l):
//  slot0 = (E0.t, E0.r, E1.t, E1.r)            even-layer coeffs, pair 64w+l
//  slot1 = (P0[R0].re, .im, P0[R0+1].re, .im)  phase layer 2i
//  slot2 = (O0 cT.t, cT.r, O1 cT.t, cT.r)      odd layers, TOP-pair coeff only
//  slot3 = P1 rows                              phase layer 2i+1
// cB (bottom-pair coeff) is recovered via __shfl_up(cT,1); lane 0 of waves 1-3
// prefetches slot2[tid-1] for the cross-wave case.
__device__ float4 g_pk[NREP][PKSTEPS * PKF4];   // ~33.8 MB static
__device__ float2 g_io[1024];  // [0,512) Pin, [512,1024) Pout

// ---------------- coefficient precompute ----------------

__device__ __forceinline__ float2 pc_coef(float th, float loss) {
  float a = sqrtf(1.0f - loss);
  float s, c;
  sincosf(th, &s, &c);
  return make_float2(a * c, a * s);
}
__device__ __forceinline__ float2 mmi_coef(float loss, float imb) {
  float a = sqrtf(1.0f - loss);
  return make_float2(a * sqrtf(0.5f + imb), a * sqrtf(0.5f - imb));
}

__global__ void precomp_kernel(const float* __restrict__ thf,
                               const float* __restrict__ thio,
                               const float* __restrict__ lpf,
                               const float* __restrict__ lpio,
                               const float* __restrict__ le,
                               const float* __restrict__ lo,
                               const float* __restrict__ ie,
                               const float* __restrict__ io2) {
  const int b   = blockIdx.x;
  const int tid = threadIdx.x;
  if (b >= NSTEPS) {
    int j = (b - NSTEPS) * 256 + tid;           // j in [0,512)
    g_io[j]       = pc_coef(thio[j],       lpio[j]);        // Pin
    g_io[j + 512] = pc_coef(thio[j + 512], lpio[j + 512]);  // Pout
    return;
  }
  const int i  = b;
  const int w  = tid >> 6, l = tid & 63;
  const int R0 = 128 * w + 2 * l;
  const int p  = 64 * w + l;
  const int L0 = 2 * i, L1 = 2 * i + 1;

  float2 e0  = mmi_coef(le[L0 * 256 + p], ie[L0 * 256 + p]);
  float2 e1  = mmi_coef(le[L1 * 256 + p], ie[L1 * 256 + p]);
  float2 p0a = pc_coef(thf[L0 * 512 + R0],     lpf[L0 * 512 + R0]);
  float2 p0b = pc_coef(thf[L0 * 512 + R0 + 1], lpf[L0 * 512 + R0 + 1]);
  float2 p1a = pc_coef(thf[L1 * 512 + R0],     lpf[L1 * 512 + R0]);
  float2 p1b = pc_coef(thf[L1 * 512 + R0 + 1], lpf[L1 * 512 + R0 + 1]);
  float2 one = make_float2(1.0f, 0.0f);
  float2 o0T = (p <= 254) ? mmi_coef(lo[L0 * 255 + p], io2[L0 * 255 + p]) : one;
  float2 o1T = (p <= 254) ? mmi_coef(lo[L1 * 255 + p], io2[L1 * 255 + p]) : one;

  float4 F0 = make_float4(e0.x,  e0.y,  e1.x,  e1.y);
  float4 F1 = make_float4(p0a.x, p0a.y, p0b.x, p0b.y);
  float4 F2 = make_float4(o0T.x, o0T.y, o1T.x, o1T.y);
  float4 F3 = make_float4(p1a.x, p1a.y, p1b.x, p1b.y);

  #pragma unroll
  for (int r = 0; r < NREP; ++r) {
    float4* base = &g_pk[r][i * PKF4] + tid;
    base[0]       = F0;
    base[256]     = F1;
    base[2 * 256] = F2;
    base[3 * 256] = F3;
  }
}

// ---------------- column propagation ----------------
// Block = 256 threads = 4 waves = one column PAIR (byte-minimal config).
// Wave w owns rows 128w..128w+127; lane l owns rows R0=128w+2l, R0+1 of both
// columns. 2-step register prefetch; per-XCD stream replica.

__device__ __forceinline__ void cmul(float2& v, float ar, float ai) {
  float xr = ar * v.x - ai * v.y;
  float xi = ar * v.y + ai * v.x;
  v.x = xr; v.y = xi;
}
__device__ __forceinline__ void mmix(float2& top, float2& bot, float t, float r) {
  float a = t * top.x - r * bot.y;
  float b = t * top.y + r * bot.x;
  float c = t * bot.x - r * top.y;
  float d = t * bot.y + r * top.x;
  top.x = a; top.y = b; bot.x = c; bot.y = d;
}
// v' = t*v + i r*o
__device__ __forceinline__ void upd(float2& v, float t, float r, float2 o) {
  float xr = t * v.x - r * o.y;
  float xi = t * v.y + r * o.x;
  v.x = xr; v.y = xi;
}

__global__ __launch_bounds__(256) void prop_kernel(float* __restrict__ out,
                                                   int write_complex) {
  __shared__ float2 sUp[2][2][4];  // [col][sid][wave]: old row 128w+127
  __shared__ float2 sDn[2][2][4];  // [col][sid][wave]: old row 128w
  const int tid = threadIdx.x;
  const int l = tid & 63, w = tid >> 6;
  const int R0 = 128 * w + 2 * l;
  const int colbase = blockIdx.x * 2;
  const int rep = blockIdx.x & (NREP - 1);
  const bool haveB = (l == 0 && w > 0);   // needs cross-wave cB from slot2[tid-1]

  float2 v[2][2];
  #pragma unroll
  for (int c = 0; c < 2; ++c)
    #pragma unroll
    for (int k = 0; k < 2; ++k)
      v[c][k] = (colbase + c == R0 + k) ? make_float2(1.0f, 0.0f)
                                        : make_float2(0.0f, 0.0f);

  // ct = TOP-pair coeff (pair 64w+l); cb from lane l-1 (pair 64w+l-1), with
  // lane0/w>0 taking the prefetched cross-wave value (cbe).
  auto odd = [&](float ctx, float cty, float cbex, float cbey, int sid) {
    float2 nb0, nb1, pt0, pt1;
    nb0.x = __shfl_down(v[0][0].x, 1); nb0.y = __shfl_down(v[0][0].y, 1);
    nb1.x = __shfl_down(v[1][0].x, 1); nb1.y = __shfl_down(v[1][0].y, 1);
    pt0.x = __shfl_up(v[0][1].x, 1);   pt0.y = __shfl_up(v[0][1].y, 1);
    pt1.x = __shfl_up(v[1][1].x, 1);   pt1.y = __shfl_up(v[1][1].y, 1);
    if (l == 0)  { sDn[0][sid][w] = v[0][0]; sDn[1][sid][w] = v[1][0]; }
    if (l == 63) { sUp[0][sid][w] = v[0][1]; sUp[1][sid][w] = v[1][1]; }
    __syncthreads();
    if (l == 63 && w < 3) { nb0 = sDn[0][sid][w + 1]; nb1 = sDn[1][sid][w + 1]; }
    if (l == 0 && w > 0)  { pt0 = sUp[0][sid][w - 1]; pt1 = sUp[1][sid][w - 1]; }
    float cbx = __shfl_up(ctx, 1);
    float cby = __shfl_up(cty, 1);
    if (haveB) { cbx = cbex; cby = cbey; }
    if (!(w == 3 && l == 63)) {          // row 511 passes through
      upd(v[0][1], ctx, cty, nb0);
      upd(v[1][1], ctx, cty, nb1);
    }
    if (!(w == 0 && l == 0)) {           // row 0 passes through
      upd(v[0][0], cbx, cby, pt0);
      upd(v[1][0], cbx, cby, pt1);
    }
  };

  auto step = [&](float4 f0, float4 f1, float4 f2, float4 f3, float4 fB) {
    mmix(v[0][0], v[0][1], f0.x, f0.y);            // E(2i)
    mmix(v[1][0], v[1][1], f0.x, f0.y);
    cmul(v[0][0], f1.x, f1.y); cmul(v[1][0], f1.x, f1.y);   // P(2i)
    cmul(v[0][1], f1.z, f1.w); cmul(v[1][1], f1.z, f1.w);
    mmix(v[0][0], v[0][1], f0.z, f0.w);            // E(2i+1)
    mmix(v[1][0], v[1][1], f0.z, f0.w);
    odd(f2.x, f2.y, fB.x, fB.y, 0);                // O(2i)
    cmul(v[0][0], f3.x, f3.y); cmul(v[1][0], f3.x, f3.y);   // P(2i+1)
    cmul(v[0][1], f3.z, f3.w); cmul(v[1][1], f3.z, f3.w);
    odd(f2.z, f2.w, fB.z, fB.w, 1);                // O(2i+1)
  };

  // Pin
  {
    float4 a = *(const float4*)(g_io + R0);
    cmul(v[0][0], a.x, a.y); cmul(v[1][0], a.x, a.y);
    cmul(v[0][1], a.z, a.w); cmul(v[1][1], a.z, a.w);
  }

  const float4* P = &g_pk[rep][0] + tid;   // step stride = PKF4
  float4 zero = make_float4(1.0f, 0.0f, 1.0f, 0.0f);
  // prologue: prefetch steps 0 and 1
  float4 a0 = P[0],    a1 = P[256],       a2 = P[512],       a3 = P[768];
  float4 b0 = P[PKF4], b1 = P[PKF4+256],  b2 = P[PKF4+512],  b3 = P[PKF4+768];
  float4 aB = zero, bB = zero;
  if (haveB) { aB = P[511]; bB = P[PKF4 + 511]; }   // slot2[tid-1]

  #pragma unroll 1
  for (int i = 0; i < NSTEPS; i += 2) {
    const float4* Q = P + (i + 2) * PKF4;          // pad steps make this safe
    float4 n0 = Q[0], n1 = Q[256], n2 = Q[512], n3 = Q[768];
    float4 nB = zero;
    if (haveB) nB = Q[511];
    step(a0, a1, a2, a3, aB);
    a0 = n0; a1 = n1; a2 = n2; a3 = n3; aB = nB;
    const float4* R = P + (i + 3) * PKF4;
    n0 = R[0]; n1 = R[256]; n2 = R[512]; n3 = R[768];
    nB = zero;
    if (haveB) nB = R[511];
    step(b0, b1, b2, b3, bB);
    b0 = n0; b1 = n1; b2 = n2; b3 = n3; bB = nB;
  }

  // Pout
  {
    float4 a = *(const float4*)(g_io + 512 + R0);
    cmul(v[0][0], a.x, a.y); cmul(v[1][0], a.x, a.y);
    cmul(v[0][1], a.z, a.w); cmul(v[1][1], a.z, a.w);
  }

  if (write_complex) {
    float2* o = (float2*)out;
    #pragma unroll
    for (int c = 0; c < 2; ++c) {
      o[(R0 + 0) * NROWS + colbase + c] = v[c][0];
      o[(R0 + 1) * NROWS + colbase + c] = v[c][1];
    }
  } else {
    // d_out = 262144 floats: real part of the complex64 matrix
    #pragma unroll
    for (int c = 0; c < 2; ++c) {
      out[(R0 + 0) * NROWS + colbase + c] = v[c][0].x;
      out[(R0 + 1) * NROWS + colbase + c] = v[c][1].x;
    }
  }
}

// ---------------- launch ----------------

extern "C" void kernel_launch(void* const* d_in, const int* in_sizes, int n_in,
                              void* d_out, int out_size, void* d_ws, size_t ws_size,
                              hipStream_t stream) {
  const float* thf  = (const float*)d_in[0];  // thetas_full     (512,512)
  const float* thio = (const float*)d_in[1];  // thetas_inout    (2,512)
  const float* lpf  = (const float*)d_in[2];  // pc_losses_full  (512,512)
  const float* lpio = (const float*)d_in[3];  // pc_losses_inout (2,512)
  const float* le   = (const float*)d_in[4];  // mmi_losses_even (512,256)
  const float* lo   = (const float*)d_in[5];  // mmi_losses_odd  (512,255)
  const float* ie   = (const float*)d_in[6];  // mmi_imb_even    (512,256)
  const float* io2  = (const float*)d_in[7];  // mmi_imb_odd     (512,255)

  const int write_complex = (out_size >= 2 * NROWS * NROWS) ? 1 : 0;

  precomp_kernel<<<NSTEPS + 2, 256, 0, stream>>>(
      thf, thio, lpf, lpio, le, lo, ie, io2);
  prop_kernel<<<NROWS / 2, 256, 0, stream>>>((float*)d_out, write_complex);
}